// Round 2
// baseline (2286.939 us; speedup 1.0000x reference)
//
#include <hip/hip_runtime.h>
#include <hip/hip_bf16.h>

#define NN 50000
#define NE 800000
#define NG 512
#define DD 128
#define MM 256
#define TT 4
#define NPASS 4
#define GHID 256

typedef __bf16 bf16x8 __attribute__((ext_vector_type(8)));
typedef float f32x4 __attribute__((ext_vector_type(4)));

// ---------------- param prep: fp32 -> bf16 (optionally transposed) ----------------

__global__ void convert_w(const float* __restrict__ in, __bf16* __restrict__ out, int n) {
    int i = blockIdx.x * 256 + threadIdx.x;
    if (i < n) out[i] = (__bf16)in[i];
}

// in[t][r][c] fp32 -> out[t][c][r] bf16
__global__ void transpose_w(const float* __restrict__ in, __bf16* __restrict__ out,
                            int Tn, int R, int C) {
    int i = blockIdx.x * 256 + threadIdx.x;
    int tot = Tn * R * C;
    if (i >= tot) return;
    int t = i / (R * C);
    int rem = i - t * R * C;
    int r = rem / C;
    int c = rem - r * C;
    out[(t * C + c) * R + r] = (__bf16)in[i];
}

// ---------------- embedding gather: fp32 master h + bf16 shadow ----------------

__global__ void embed_kernel(const int* __restrict__ node_types,
                             const float* __restrict__ emb,
                             float* __restrict__ hf, __bf16* __restrict__ hb) {
    int t = blockIdx.x * 256 + threadIdx.x;
    if (t >= NN * DD) return;
    int node = t >> 7, d = t & 127;
    float v = emb[node_types[node] * DD + d];
    hf[t] = v;
    hb[t] = (__bf16)v;
}

// ---------------- CSR build ----------------

__global__ void hist_kernel(const int* __restrict__ src, int* __restrict__ counts) {
    int e = blockIdx.x * 256 + threadIdx.x;
    if (e < NE) atomicAdd(&counts[src[e]], 1);
}

__global__ void scan_kernel(const int* __restrict__ counts,
                            int* __restrict__ offsets, int* __restrict__ cursor) {
    __shared__ int smem[1024];
    __shared__ int carry;
    if (threadIdx.x == 0) carry = 0;
    __syncthreads();
    for (int base = 0; base < NN; base += 1024) {
        int i = base + threadIdx.x;
        int v = (i < NN) ? counts[i] : 0;
        smem[threadIdx.x] = v;
        __syncthreads();
        for (int off = 1; off < 1024; off <<= 1) {
            int t = (threadIdx.x >= off) ? smem[threadIdx.x - off] : 0;
            __syncthreads();
            smem[threadIdx.x] += t;
            __syncthreads();
        }
        int excl = smem[threadIdx.x] - v + carry;
        if (i < NN) { offsets[i] = excl; cursor[i] = excl; }
        __syncthreads();
        if (threadIdx.x == 0) carry += smem[1023];
        __syncthreads();
    }
    if (threadIdx.x == 0) offsets[NN] = carry;
}

__global__ void fill_kernel(const int* __restrict__ src, const int* __restrict__ dst,
                            const int* __restrict__ et, int* __restrict__ cursor,
                            int* __restrict__ edge_row) {
    int e = blockIdx.x * 256 + threadIdx.x;
    if (e >= NE) return;
    int pos = atomicAdd(&cursor[src[e]], 1);
    edge_row[pos] = et[e] * NN + dst[e];
}

// ---------------- MFMA GEMM: C = A @ BT^T + bias(fp32), C bf16 ----------------
// A:(nrows,K) bf16 rm; BT:(ncols,K) bf16 rm; blockIdx.z offsets BT/bias/C.
// 256 thr = 4 waves; block tile 64x64; wave 16x64.
__global__ void gemm_bt(const __bf16* __restrict__ A, const __bf16* __restrict__ BT,
                        const float* __restrict__ bias, __bf16* __restrict__ C,
                        int nrows, int ncols, int K) {
    int z = blockIdx.z;
    BT   += (size_t)z * ncols * K;
    bias += (size_t)z * ncols;
    C    += (size_t)z * nrows * ncols;

    int wave = threadIdx.x >> 6;
    int lane = threadIdx.x & 63;
    int r0 = blockIdx.x * 64 + wave * 16;
    int c0 = blockIdx.y * 64;
    int lm = lane & 15, lq = lane >> 4;

    f32x4 acc[4] = {};
    int arow = r0 + lm;
    if (arow >= nrows) arow = nrows - 1;   // clamp; stores guarded
    const __bf16* Arow = A + (size_t)arow * K + lq * 8;

    for (int k0 = 0; k0 < K; k0 += 32) {
        bf16x8 a = *(const bf16x8*)(Arow + k0);
#pragma unroll
        for (int nt = 0; nt < 4; ++nt) {
            int ncol = c0 + nt * 16 + lm;
            bf16x8 b = *(const bf16x8*)(BT + (size_t)ncol * K + k0 + lq * 8);
            acc[nt] = __builtin_amdgcn_mfma_f32_16x16x32_bf16(a, b, acc[nt], 0, 0, 0);
        }
    }
#pragma unroll
    for (int nt = 0; nt < 4; ++nt) {
        int col = c0 + nt * 16 + lm;
        float bv = bias[col];
#pragma unroll
        for (int i = 0; i < 4; ++i) {
            int row = r0 + lq * 4 + i;
            if (row < nrows) C[(size_t)row * ncols + col] = (__bf16)(acc[nt][i] + bv);
        }
    }
}

// readout: rowscale by attn, atomicAdd fp32 into hgraph[node2graph[row]]
__global__ void gemm_readout(const __bf16* __restrict__ A, const __bf16* __restrict__ BT,
                             const float* __restrict__ bias, const float* __restrict__ attn,
                             const int* __restrict__ node2graph, float* __restrict__ hgraph,
                             int nrows, int ncols, int K) {
    int wave = threadIdx.x >> 6;
    int lane = threadIdx.x & 63;
    int r0 = blockIdx.x * 64 + wave * 16;
    int c0 = blockIdx.y * 64;
    int lm = lane & 15, lq = lane >> 4;

    f32x4 acc[4] = {};
    int arow = r0 + lm;
    if (arow >= nrows) arow = nrows - 1;
    const __bf16* Arow = A + (size_t)arow * K + lq * 8;

    for (int k0 = 0; k0 < K; k0 += 32) {
        bf16x8 a = *(const bf16x8*)(Arow + k0);
#pragma unroll
        for (int nt = 0; nt < 4; ++nt) {
            int ncol = c0 + nt * 16 + lm;
            bf16x8 b = *(const bf16x8*)(BT + (size_t)ncol * K + k0 + lq * 8);
            acc[nt] = __builtin_amdgcn_mfma_f32_16x16x32_bf16(a, b, acc[nt], 0, 0, 0);
        }
    }
#pragma unroll
    for (int nt = 0; nt < 4; ++nt) {
        int col = c0 + nt * 16 + lm;
        float bv = bias[col];
#pragma unroll
        for (int i = 0; i < 4; ++i) {
            int row = r0 + lq * 4 + i;
            if (row < nrows) {
                float v = (acc[nt][i] + bv) * attn[row];
                atomicAdd(&hgraph[(size_t)node2graph[row] * GHID + col], v);
            }
        }
    }
}

// ---------------- edge aggregation (CSR, atomic-free) ----------------
__global__ void aggregate_kernel(const int* __restrict__ offsets, const int* __restrict__ edge_row,
                                 const __bf16* __restrict__ msgs_all, __bf16* __restrict__ msgs) {
    int node = blockIdx.x;
    int m = threadIdx.x;
    int beg = offsets[node], end = offsets[node + 1];
    float acc = 0.f;
    for (int j = beg; j < end; ++j) {
        int row = edge_row[j];
        acc += (float)msgs_all[(size_t)row * MM + m];
    }
    msgs[(size_t)node * MM + m] = (__bf16)fmaxf(acc, 0.f);
}

// ---------------- GRU elementwise: fp32 master h + bf16 shadow ----------------
__global__ void gru_ew(const __bf16* __restrict__ gi, const __bf16* __restrict__ gh,
                       float* __restrict__ hf, __bf16* __restrict__ hb) {
    int t = blockIdx.x * 256 + threadIdx.x;
    if (t >= NN * DD) return;
    int node = t >> 7, d = t & 127;
    size_t b = (size_t)node * 384;
    float ir = (float)gi[b + d], iz = (float)gi[b + 128 + d], inn = (float)gi[b + 256 + d];
    float hr = (float)gh[b + d], hz = (float)gh[b + 128 + d], hn = (float)gh[b + 256 + d];
    float r = 1.f / (1.f + expf(-(ir + hr)));
    float z = 1.f / (1.f + expf(-(iz + hz)));
    float nv = tanhf(inn + r * hn);
    float hnew = (1.f - z) * nv + z * hf[t];
    hf[t] = hnew;
    hb[t] = (__bf16)hnew;
}

// ---------------- per-node gate scalar ----------------
__global__ void attn_kernel(const float* __restrict__ hf, const float* __restrict__ w_gate,
                            const float* __restrict__ b_gate, float* __restrict__ attn) {
    int node = blockIdx.x * 4 + (threadIdx.x >> 6);
    int lane = threadIdx.x & 63;
    if (node >= NN) return;
    size_t base = (size_t)node * DD;
    float s = hf[base + lane * 2] * w_gate[lane * 2]
            + hf[base + lane * 2 + 1] * w_gate[lane * 2 + 1];
    for (int off = 32; off; off >>= 1) s += __shfl_down(s, off);
    if (lane == 0) attn[node] = 1.f / (1.f + expf(-(s + b_gate[0])));
}

// ---------------- launch ----------------

extern "C" void kernel_launch(void* const* d_in, const int* in_sizes, int n_in,
                              void* d_out, int out_size, void* d_ws, size_t ws_size,
                              hipStream_t stream) {
    const int*   node_types = (const int*)d_in[0];
    const int*   edge_src   = (const int*)d_in[1];
    const int*   edge_dst   = (const int*)d_in[2];
    const int*   edge_type  = (const int*)d_in[3];
    const int*   node2graph = (const int*)d_in[4];
    const float* emb        = (const float*)d_in[5];
    const float* W_msg      = (const float*)d_in[6];
    const float* b_msg      = (const float*)d_in[7];
    const float* W_ih       = (const float*)d_in[8];   // (384,256) == B^T for gi
    const float* W_hh       = (const float*)d_in[9];   // (384,128) == B^T for gh
    const float* b_ih       = (const float*)d_in[10];
    const float* b_hh       = (const float*)d_in[11];
    const float* w_gate     = (const float*)d_in[12];
    const float* b_gate     = (const float*)d_in[13];
    const float* W_g        = (const float*)d_in[14];
    const float* b_g        = (const float*)d_in[15];

    float* hf     = (float*)d_out;                    // output 0 (fp32 master h)
    float* hgraph = hf + (size_t)NN * DD;             // output 1 (fp32 accum)

    char* ws = (char*)d_ws;
    size_t off = 0;
    auto alloc = [&](size_t bytes) -> char* {
        char* p = ws + off;
        off += (bytes + 255) & ~(size_t)255;
        return p;
    };
    __bf16* msgs_all = (__bf16*)alloc((size_t)TT * NN * MM * 2);   // 102.4 MB
    // gi/gh alias into msgs_all region: aggregate (last reader of msgs_all)
    // completes before the gi/gh GEMMs write here (stream-ordered).
    __bf16* gi = msgs_all;                                         // 38.4 MB
    __bf16* gh = msgs_all + (size_t)NN * 384;                      // 38.4 MB
    __bf16* msgs    = (__bf16*)alloc((size_t)NN * MM * 2);         // 25.6 MB
    __bf16* hb      = (__bf16*)alloc((size_t)NN * DD * 2);         // 12.8 MB
    __bf16* WmT     = (__bf16*)alloc((size_t)TT * MM * DD * 2);
    __bf16* WgT     = (__bf16*)alloc((size_t)GHID * DD * 2);
    __bf16* Wih_b   = (__bf16*)alloc((size_t)384 * MM * 2);
    __bf16* Whh_b   = (__bf16*)alloc((size_t)384 * DD * 2);
    float*  attn    = (float*)alloc((size_t)NN * 4);
    int*    counts  = (int*)alloc((size_t)(NN + 1) * 4);
    int*    offsets = (int*)alloc((size_t)(NN + 1) * 4);
    int*    cursor  = (int*)alloc((size_t)(NN + 1) * 4);
    int*    edge_row= (int*)alloc((size_t)NE * 4);

    hipMemsetAsync(counts, 0, (NN + 1) * 4, stream);
    hipMemsetAsync(hgraph, 0, (size_t)NG * GHID * 4, stream);

    transpose_w<<<(TT * DD * MM + 255) / 256, 256, 0, stream>>>(W_msg, WmT, TT, DD, MM);
    transpose_w<<<(DD * GHID + 255) / 256, 256, 0, stream>>>(W_g, WgT, 1, DD, GHID);
    convert_w<<<(384 * MM + 255) / 256, 256, 0, stream>>>(W_ih, Wih_b, 384 * MM);
    convert_w<<<(384 * DD + 255) / 256, 256, 0, stream>>>(W_hh, Whh_b, 384 * DD);
    embed_kernel<<<(NN * DD + 255) / 256, 256, 0, stream>>>(node_types, emb, hf, hb);

    hist_kernel<<<(NE + 255) / 256, 256, 0, stream>>>(edge_src, counts);
    scan_kernel<<<1, 1024, 0, stream>>>(counts, offsets, cursor);
    fill_kernel<<<(NE + 255) / 256, 256, 0, stream>>>(edge_src, edge_dst, edge_type, cursor, edge_row);

    dim3 blk(256);
    int rt = (NN + 63) / 64;  // 782 row tiles
    for (int p = 0; p < NPASS; ++p) {
        gemm_bt<<<dim3(rt, MM / 64, TT), blk, 0, stream>>>(hb, WmT, b_msg, msgs_all, NN, MM, DD);
        aggregate_kernel<<<NN, 256, 0, stream>>>(offsets, edge_row, msgs_all, msgs);
        gemm_bt<<<dim3(rt, 384 / 64, 1), blk, 0, stream>>>(msgs, Wih_b, b_ih, gi, NN, 384, MM);
        gemm_bt<<<dim3(rt, 384 / 64, 1), blk, 0, stream>>>(hb, Whh_b, b_hh, gh, NN, 384, DD);
        gru_ew<<<(NN * DD + 255) / 256, 256, 0, stream>>>(gi, gh, hf, hb);
    }

    attn_kernel<<<(NN + 3) / 4, 256, 0, stream>>>(hf, w_gate, b_gate, attn);
    gemm_readout<<<dim3(rt, GHID / 64, 1), blk, 0, stream>>>(hb, WgT, b_g, attn, node2graph, hgraph, NN, GHID, DD);
}

// Round 3
// 1798.991 us; speedup vs baseline: 1.2712x; 1.2712x over previous
//
#include <hip/hip_runtime.h>
#include <hip/hip_bf16.h>

#define NN 50000
#define NE 800000
#define NG 512
#define DD 128
#define MM 256
#define TT 4
#define NPASS 4
#define GHID 256
#define NKEY (NN * TT)          // CSR keys: src*4 + type

typedef __bf16 bf16x8 __attribute__((ext_vector_type(8)));
typedef float f32x4 __attribute__((ext_vector_type(4)));

// ---------------- param prep ----------------

__global__ void convert_w(const float* __restrict__ in, __bf16* __restrict__ out, int n) {
    int i = blockIdx.x * 256 + threadIdx.x;
    if (i < n) out[i] = (__bf16)in[i];
}

// in (R,C) fp32 -> out (C,R) bf16
__global__ void transpose_w(const float* __restrict__ in, __bf16* __restrict__ out,
                            int R, int C) {
    int i = blockIdx.x * 256 + threadIdx.x;
    if (i >= R * C) return;
    int r = i / C, c = i - r * C;
    out[c * R + r] = (__bf16)in[i];
}

__global__ void embed_kernel(const int* __restrict__ node_types,
                             const float* __restrict__ emb,
                             float* __restrict__ hf, __bf16* __restrict__ hb) {
    int t = blockIdx.x * 256 + threadIdx.x;
    if (t >= NN * DD) return;
    int node = t >> 7, d = t & 127;
    float v = emb[node_types[node] * DD + d];
    hf[t] = v;
    hb[t] = (__bf16)v;
}

// ---------------- CSR build (keyed by src*4+type) ----------------

__global__ void hist_kernel(const int* __restrict__ src, const int* __restrict__ et,
                            int* __restrict__ counts) {
    int e = blockIdx.x * 256 + threadIdx.x;
    if (e < NE) atomicAdd(&counts[src[e] * TT + et[e]], 1);
}

__global__ void ghist_kernel(const int* __restrict__ n2g, int* __restrict__ gcounts) {
    int i = blockIdx.x * 256 + threadIdx.x;
    if (i < NN) atomicAdd(&gcounts[n2g[i]], 1);
}

// hierarchical scan: scan1 (local excl into offsets, block sums), scan2 (scan block
// sums, write total sentinel), scan3 (add block base, copy to cursor)
__global__ void scan1(const int* __restrict__ counts, int* __restrict__ offsets,
                      int* __restrict__ bsum, int n) {
    __shared__ int sm[256];
    int i = blockIdx.x * 256 + threadIdx.x;
    int v = (i < n) ? counts[i] : 0;
    sm[threadIdx.x] = v;
    __syncthreads();
    for (int off = 1; off < 256; off <<= 1) {
        int t = (threadIdx.x >= off) ? sm[threadIdx.x - off] : 0;
        __syncthreads();
        sm[threadIdx.x] += t;
        __syncthreads();
    }
    if (i < n) offsets[i] = sm[threadIdx.x] - v;   // local exclusive
    if (threadIdx.x == 255) bsum[blockIdx.x] = sm[255];
}

__global__ void scan2(int* __restrict__ bsum, int nb, int* __restrict__ offsets, int n) {
    __shared__ int sm[1024];
    int v = (threadIdx.x < nb) ? bsum[threadIdx.x] : 0;
    sm[threadIdx.x] = v;
    __syncthreads();
    for (int off = 1; off < 1024; off <<= 1) {
        int t = (threadIdx.x >= off) ? sm[threadIdx.x - off] : 0;
        __syncthreads();
        sm[threadIdx.x] += t;
        __syncthreads();
    }
    if (threadIdx.x < nb) bsum[threadIdx.x] = sm[threadIdx.x] - v;  // exclusive
    if (threadIdx.x == 1023) offsets[n] = sm[1023];                 // total sentinel
}

__global__ void scan3(int* __restrict__ offsets, const int* __restrict__ bsum,
                      int* __restrict__ cursor, int n) {
    int i = blockIdx.x * 256 + threadIdx.x;
    if (i < n) {
        int o = offsets[i] + bsum[blockIdx.x];
        offsets[i] = o;
        if (cursor) cursor[i] = o;
    }
}

__global__ void fill_kernel(const int* __restrict__ src, const int* __restrict__ dst,
                            const int* __restrict__ et, int* __restrict__ cursor,
                            int* __restrict__ elist) {
    int e = blockIdx.x * 256 + threadIdx.x;
    if (e >= NE) return;
    int pos = atomicAdd(&cursor[src[e] * TT + et[e]], 1);
    elist[pos] = dst[e];
}

// ---------------- per-pass: X[node][t][:] = sum of h[dst] over type-t out-edges ----------------
// one block (128 thr) per node; type segments are contiguous in elist (no predication)
__global__ void agg2_kernel(const int* __restrict__ offsets, const int* __restrict__ elist,
                            const __bf16* __restrict__ hb, __bf16* __restrict__ X) {
    int node = blockIdx.x;
    int d = threadIdx.x;
    int base = node * TT;
    for (int t = 0; t < TT; ++t) {
        int beg = offsets[base + t], end = offsets[base + t + 1];
        float acc = 0.f;
        for (int j = beg; j < end; ++j) {
            int dst = elist[j];
            acc += (float)hb[(size_t)dst * DD + d];
        }
        X[((size_t)node * TT + t) * DD + d] = (__bf16)acc;
    }
}

// ---------------- MFMA GEMM: C = A(nrows,K) @ BT(ncols,K)^T + bias, bf16 out ----------------
__global__ void gemm_bt(const __bf16* __restrict__ A, const __bf16* __restrict__ BT,
                        const float* __restrict__ bias, __bf16* __restrict__ C,
                        int nrows, int ncols, int K) {
    int wave = threadIdx.x >> 6;
    int lane = threadIdx.x & 63;
    int r0 = blockIdx.x * 64 + wave * 16;
    int c0 = blockIdx.y * 64;
    int lm = lane & 15, lq = lane >> 4;

    f32x4 acc[4] = {};
    int arow = r0 + lm;
    if (arow >= nrows) arow = nrows - 1;
    const __bf16* Arow = A + (size_t)arow * K + lq * 8;

    for (int k0 = 0; k0 < K; k0 += 32) {
        bf16x8 a = *(const bf16x8*)(Arow + k0);
#pragma unroll
        for (int nt = 0; nt < 4; ++nt) {
            int ncol = c0 + nt * 16 + lm;
            bf16x8 b = *(const bf16x8*)(BT + (size_t)ncol * K + k0 + lq * 8);
            acc[nt] = __builtin_amdgcn_mfma_f32_16x16x32_bf16(a, b, acc[nt], 0, 0, 0);
        }
    }
#pragma unroll
    for (int nt = 0; nt < 4; ++nt) {
        int col = c0 + nt * 16 + lm;
        float bv = bias[col];
#pragma unroll
        for (int i = 0; i < 4; ++i) {
            int row = r0 + lq * 4 + i;
            if (row < nrows) C[(size_t)row * ncols + col] = (__bf16)(acc[nt][i] + bv);
        }
    }
}

// msgs = relu(X @ WcatT^T + sum_t n_t * b_msg[t]); K=512, ncols=256
__global__ void msgs_gemm(const __bf16* __restrict__ A, const __bf16* __restrict__ BT,
                          const float* __restrict__ b_msg, const int* __restrict__ offsets,
                          __bf16* __restrict__ C) {
    const int K = 512, ncols = MM;
    int wave = threadIdx.x >> 6;
    int lane = threadIdx.x & 63;
    int r0 = blockIdx.x * 64 + wave * 16;
    int c0 = blockIdx.y * 64;
    int lm = lane & 15, lq = lane >> 4;

    f32x4 acc[4] = {};
    int arow = r0 + lm;
    if (arow >= NN) arow = NN - 1;
    const __bf16* Arow = A + (size_t)arow * K + lq * 8;

    for (int k0 = 0; k0 < K; k0 += 32) {
        bf16x8 a = *(const bf16x8*)(Arow + k0);
#pragma unroll
        for (int nt = 0; nt < 4; ++nt) {
            int ncol = c0 + nt * 16 + lm;
            bf16x8 b = *(const bf16x8*)(BT + (size_t)ncol * K + k0 + lq * 8);
            acc[nt] = __builtin_amdgcn_mfma_f32_16x16x32_bf16(a, b, acc[nt], 0, 0, 0);
        }
    }
#pragma unroll
    for (int i = 0; i < 4; ++i) {
        int row = r0 + lq * 4 + i;
        if (row >= NN) continue;
        int ob = row * TT;
        int o0 = offsets[ob], o1 = offsets[ob + 1], o2 = offsets[ob + 2],
            o3 = offsets[ob + 3], o4 = offsets[ob + 4];
        float n0 = (float)(o1 - o0), n1 = (float)(o2 - o1),
              n2 = (float)(o3 - o2), n3 = (float)(o4 - o3);
#pragma unroll
        for (int nt = 0; nt < 4; ++nt) {
            int col = c0 + nt * 16 + lm;
            float bias = n0 * b_msg[col] + n1 * b_msg[MM + col]
                       + n2 * b_msg[2 * MM + col] + n3 * b_msg[3 * MM + col];
            C[(size_t)row * ncols + col] = (__bf16)fmaxf(acc[nt][i] + bias, 0.f);
        }
    }
}

// ---------------- GRU elementwise ----------------
__global__ void gru_ew(const __bf16* __restrict__ gi, const __bf16* __restrict__ gh,
                       float* __restrict__ hf, __bf16* __restrict__ hb) {
    int t = blockIdx.x * 256 + threadIdx.x;
    if (t >= NN * DD) return;
    int node = t >> 7, d = t & 127;
    size_t b = (size_t)node * 384;
    float ir = (float)gi[b + d], iz = (float)gi[b + 128 + d], inn = (float)gi[b + 256 + d];
    float hr = (float)gh[b + d], hz = (float)gh[b + 128 + d], hn = (float)gh[b + 256 + d];
    float r = 1.f / (1.f + expf(-(ir + hr)));
    float z = 1.f / (1.f + expf(-(iz + hz)));
    float nv = tanhf(inn + r * hn);
    float hnew = (1.f - z) * nv + z * hf[t];
    hf[t] = hnew;
    hb[t] = (__bf16)hnew;
}

// ---------------- readout: attn, segment-sum, tiny fp32 GEMM ----------------
__global__ void attn_kernel(const float* __restrict__ hf, const float* __restrict__ w_gate,
                            const float* __restrict__ b_gate, float* __restrict__ attn) {
    int node = blockIdx.x * 4 + (threadIdx.x >> 6);
    int lane = threadIdx.x & 63;
    if (node >= NN) return;
    size_t base = (size_t)node * DD;
    float s = hf[base + lane * 2] * w_gate[lane * 2]
            + hf[base + lane * 2 + 1] * w_gate[lane * 2 + 1];
    for (int off = 32; off; off >>= 1) s += __shfl_down(s, off);
    if (lane == 0) attn[node] = 1.f / (1.f + expf(-(s + b_gate[0])));
}

// one block (128 thr) per graph; node2graph is sorted so nodes are contiguous
__global__ void segsum_kernel(const int* __restrict__ goff, const float* __restrict__ attn,
                              const float* __restrict__ hf, float* __restrict__ sg,
                              float* __restrict__ asumg) {
    int g = blockIdx.x;
    int d = threadIdx.x;
    int beg = goff[g], end = goff[g + 1];
    float s = 0.f, asum = 0.f;
    for (int i = beg; i < end; ++i) {
        float a = attn[i];
        s += a * hf[(size_t)i * DD + d];
        if (d == 0) asum += a;
    }
    sg[g * DD + d] = s;
    if (d == 0) asumg[g] = asum;
}

// h_graph[g][m] = sum_d sg[g][d]*W_g[d][m] + asum[g]*b_g[m]   (fp32, exact-ish)
__global__ void readout_kernel(const float* __restrict__ sg, const float* __restrict__ asumg,
                               const float* __restrict__ W_g, const float* __restrict__ b_g,
                               float* __restrict__ hgraph) {
    int g = blockIdx.x;
    int m = threadIdx.x;
    float acc = asumg[g] * b_g[m];
    for (int d = 0; d < DD; ++d) acc += sg[g * DD + d] * W_g[d * GHID + m];
    hgraph[g * GHID + m] = acc;
}

// ---------------- launch ----------------

extern "C" void kernel_launch(void* const* d_in, const int* in_sizes, int n_in,
                              void* d_out, int out_size, void* d_ws, size_t ws_size,
                              hipStream_t stream) {
    const int*   node_types = (const int*)d_in[0];
    const int*   edge_src   = (const int*)d_in[1];
    const int*   edge_dst   = (const int*)d_in[2];
    const int*   edge_type  = (const int*)d_in[3];
    const int*   node2graph = (const int*)d_in[4];
    const float* emb        = (const float*)d_in[5];
    const float* W_msg      = (const float*)d_in[6];   // (T,D,M) == (512,256) flattened
    const float* b_msg      = (const float*)d_in[7];   // (T,M)
    const float* W_ih       = (const float*)d_in[8];   // (384,256) == B^T for gi
    const float* W_hh       = (const float*)d_in[9];   // (384,128) == B^T for gh
    const float* b_ih       = (const float*)d_in[10];
    const float* b_hh       = (const float*)d_in[11];
    const float* w_gate     = (const float*)d_in[12];
    const float* b_gate     = (const float*)d_in[13];
    const float* W_g        = (const float*)d_in[14];  // (128,256)
    const float* b_g        = (const float*)d_in[15];

    float* hf     = (float*)d_out;           // output 0: h (fp32 master)
    float* hgraph = hf + (size_t)NN * DD;    // output 1: fully written by readout

    char* ws = (char*)d_ws;
    size_t off = 0;
    auto alloc = [&](size_t bytes) -> char* {
        char* p = ws + off;
        off += (bytes + 255) & ~(size_t)255;
        return p;
    };
    // total ~134 MB (< the ~146 MB proven available in R2)
    __bf16* X       = (__bf16*)alloc((size_t)NN * 512 * 2);   // 51.2 MB
    __bf16* gi      = X;                                      // aliases X (dead after msgs_gemm)
    __bf16* msgs    = (__bf16*)alloc((size_t)NN * MM * 2);    // 25.6 MB
    __bf16* gh      = (__bf16*)alloc((size_t)NN * 384 * 2);   // 38.4 MB
    __bf16* hb      = (__bf16*)alloc((size_t)NN * DD * 2);    // 12.8 MB
    __bf16* WcatT   = (__bf16*)alloc((size_t)MM * 512 * 2);   // 256 KB
    __bf16* Wih_b   = (__bf16*)alloc((size_t)384 * MM * 2);
    __bf16* Whh_b   = (__bf16*)alloc((size_t)384 * DD * 2);
    float*  attn    = (float*)alloc((size_t)NN * 4);
    float*  sg      = (float*)alloc((size_t)NG * DD * 4);
    float*  asumg   = (float*)alloc((size_t)NG * 4);
    int*    counts  = (int*)alloc((size_t)(NKEY + 1) * 4);
    int*    offsets = (int*)alloc((size_t)(NKEY + 1) * 4);
    int*    cursor  = (int*)alloc((size_t)(NKEY + 1) * 4);
    int*    bsum    = (int*)alloc((size_t)1024 * 4);
    int*    elist   = (int*)alloc((size_t)NE * 4);            // 3.2 MB
    int*    gcounts = (int*)alloc((size_t)(NG + 1) * 4);
    int*    goff    = (int*)alloc((size_t)(NG + 1) * 4);
    int*    gbsum   = (int*)alloc((size_t)8 * 4);

    hipMemsetAsync(counts, 0, (NKEY + 1) * 4, stream);
    hipMemsetAsync(gcounts, 0, (NG + 1) * 4, stream);

    // param prep
    transpose_w<<<(TT * DD * MM + 255) / 256, 256, 0, stream>>>(W_msg, WcatT, 512, MM);
    convert_w<<<(384 * MM + 255) / 256, 256, 0, stream>>>(W_ih, Wih_b, 384 * MM);
    convert_w<<<(384 * DD + 255) / 256, 256, 0, stream>>>(W_hh, Whh_b, 384 * DD);
    embed_kernel<<<(NN * DD + 255) / 256, 256, 0, stream>>>(node_types, emb, hf, hb);

    // edge CSR keyed by src*4+type
    int nbE = (NKEY + 255) / 256;   // 782
    hist_kernel<<<(NE + 255) / 256, 256, 0, stream>>>(edge_src, edge_type, counts);
    scan1<<<nbE, 256, 0, stream>>>(counts, offsets, bsum, NKEY);
    scan2<<<1, 1024, 0, stream>>>(bsum, nbE, offsets, NKEY);
    scan3<<<nbE, 256, 0, stream>>>(offsets, bsum, cursor, NKEY);
    fill_kernel<<<(NE + 255) / 256, 256, 0, stream>>>(edge_src, edge_dst, edge_type, cursor, elist);

    // graph CSR (node2graph sorted -> offsets only)
    int nbG = (NG + 255) / 256;     // 2
    ghist_kernel<<<(NN + 255) / 256, 256, 0, stream>>>(node2graph, gcounts);
    scan1<<<nbG, 256, 0, stream>>>(gcounts, goff, gbsum, NG);
    scan2<<<1, 1024, 0, stream>>>(gbsum, nbG, goff, NG);
    scan3<<<nbG, 256, 0, stream>>>(goff, gbsum, (int*)nullptr, NG);

    dim3 blk(256);
    int rt = (NN + 63) / 64;  // 782
    for (int p = 0; p < NPASS; ++p) {
        agg2_kernel<<<NN, 128, 0, stream>>>(offsets, elist, hb, X);
        msgs_gemm<<<dim3(rt, MM / 64), blk, 0, stream>>>(X, WcatT, b_msg, offsets, msgs);
        gemm_bt<<<dim3(rt, 384 / 64), blk, 0, stream>>>(msgs, Wih_b, b_ih, gi, NN, 384, MM);
        gemm_bt<<<dim3(rt, 384 / 64), blk, 0, stream>>>(hb, Whh_b, b_hh, gh, NN, 384, DD);
        gru_ew<<<(NN * DD + 255) / 256, 256, 0, stream>>>(gi, gh, hf, hb);
    }

    attn_kernel<<<(NN + 3) / 4, 256, 0, stream>>>(hf, w_gate, b_gate, attn);
    segsum_kernel<<<NG, 128, 0, stream>>>(goff, attn, hf, sg, asumg);
    readout_kernel<<<NG, GHID, 0, stream>>>(sg, asumg, W_g, b_g, hgraph);
}

// Round 4
// 1384.751 us; speedup vs baseline: 1.6515x; 1.2991x over previous
//
#include <hip/hip_runtime.h>
#include <hip/hip_bf16.h>

#define NN 50000
#define NE 800000
#define NG 512
#define DD 128
#define MM 256
#define TT 4
#define NPASS 4
#define GHID 256
#define NKEY (NN * TT)          // CSR keys: src*4 + type

typedef __bf16 bf16x2 __attribute__((ext_vector_type(2)));
typedef __bf16 bf16x8 __attribute__((ext_vector_type(8)));
typedef float f32x4 __attribute__((ext_vector_type(4)));

// ================= setup: swizzled weights =================
// WK for msgs GEMM (K=512 -> 16 chunks of 32): WK[((c*4+lq)*256+col)*8+j] = W_msg[k*256+col], k=(c*4+lq)*8+j
__global__ void build_WK(const float* __restrict__ W_msg, __bf16* __restrict__ WK) {
    int i = blockIdx.x * 256 + threadIdx.x;           // 131072
    if (i >= 16 * 4 * 256 * 8) return;
    int j = i & 7, col = (i >> 3) & 255, g = i >> 11; // g=c*4+lq
    int k = g * 8 + j;
    WK[i] = (__bf16)W_msg[k * 256 + col];
}

// WB for fused GRU GEMM: 512 cols x K=384 (12 chunks). cols: [0,256)=r|z pre (Wih+Whh),
// [256,384)=i_n (Wih only), [384,512)=h_n (Whh only). k<256 -> msgs part, k>=256 -> hb part.
__global__ void build_WB(const float* __restrict__ W_ih, const float* __restrict__ W_hh,
                         __bf16* __restrict__ WB) {
    int i = blockIdx.x * 256 + threadIdx.x;           // 196608
    if (i >= 12 * 4 * 512 * 8) return;
    int j = i & 7, col = (i >> 3) & 511, g = i >> 12; // g=c*4+lq
    int k = g * 8 + j;                                // 0..383
    float v = 0.f;
    if (col < 256) {
        v = (k < 256) ? W_ih[col * 256 + k] : W_hh[col * 128 + (k - 256)];
    } else if (col < 384) {
        if (k < 256) v = W_ih[col * 256 + k];
    } else {
        if (k >= 256) v = W_hh[(col - 128) * 128 + (k - 256)];
    }
    WB[i] = (__bf16)v;
}

__global__ void build_bias512(const float* __restrict__ b_ih, const float* __restrict__ b_hh,
                              float* __restrict__ b512) {
    int c = blockIdx.x * 256 + threadIdx.x;
    if (c >= 512) return;
    float v;
    if (c < 256) v = b_ih[c] + b_hh[c];
    else if (c < 384) v = b_ih[c];
    else v = b_hh[c - 128];
    b512[c] = v;
}

// ================= embedding =================
__global__ void embed_kernel(const int* __restrict__ node_types,
                             const float* __restrict__ emb,
                             float* __restrict__ hf, __bf16* __restrict__ Acat) {
    int t = blockIdx.x * 256 + threadIdx.x;
    if (t >= NN * DD) return;
    int node = t >> 7, d = t & 127;
    float v = emb[node_types[node] * DD + d];
    hf[t] = v;
    Acat[(size_t)node * 384 + 256 + d] = (__bf16)v;
}

// ================= CSR build (keyed by src*4+type) =================
__global__ void hist_kernel(const int* __restrict__ src, const int* __restrict__ et,
                            int* __restrict__ counts) {
    int e = blockIdx.x * 256 + threadIdx.x;
    if (e < NE) atomicAdd(&counts[src[e] * TT + et[e]], 1);
}

__global__ void ghist_kernel(const int* __restrict__ n2g, int* __restrict__ gcounts) {
    int i = blockIdx.x * 256 + threadIdx.x;
    if (i < NN) atomicAdd(&gcounts[n2g[i]], 1);
}

__global__ void scan1(const int* __restrict__ counts, int* __restrict__ offsets,
                      int* __restrict__ bsum, int n) {
    __shared__ int sm[256];
    int i = blockIdx.x * 256 + threadIdx.x;
    int v = (i < n) ? counts[i] : 0;
    sm[threadIdx.x] = v;
    __syncthreads();
    for (int off = 1; off < 256; off <<= 1) {
        int t = (threadIdx.x >= off) ? sm[threadIdx.x - off] : 0;
        __syncthreads();
        sm[threadIdx.x] += t;
        __syncthreads();
    }
    if (i < n) offsets[i] = sm[threadIdx.x] - v;
    if (threadIdx.x == 255) bsum[blockIdx.x] = sm[255];
}

__global__ void scan2(int* __restrict__ bsum, int nb, int* __restrict__ offsets, int n) {
    __shared__ int sm[1024];
    int v = (threadIdx.x < nb) ? bsum[threadIdx.x] : 0;
    sm[threadIdx.x] = v;
    __syncthreads();
    for (int off = 1; off < 1024; off <<= 1) {
        int t = (threadIdx.x >= off) ? sm[threadIdx.x - off] : 0;
        __syncthreads();
        sm[threadIdx.x] += t;
        __syncthreads();
    }
    if (threadIdx.x < nb) bsum[threadIdx.x] = sm[threadIdx.x] - v;
    if (threadIdx.x == 1023) offsets[n] = sm[1023];
}

__global__ void scan3(int* __restrict__ offsets, const int* __restrict__ bsum,
                      int* __restrict__ cursor, int n) {
    int i = blockIdx.x * 256 + threadIdx.x;
    if (i < n) {
        int o = offsets[i] + bsum[blockIdx.x];
        offsets[i] = o;
        if (cursor) cursor[i] = o;
    }
}

__global__ void fill_kernel(const int* __restrict__ src, const int* __restrict__ dst,
                            const int* __restrict__ et, int* __restrict__ cursor,
                            int* __restrict__ elist) {
    int e = blockIdx.x * 256 + threadIdx.x;
    if (e >= NE) return;
    int pos = atomicAdd(&cursor[src[e] * TT + et[e]], 1);
    elist[pos] = dst[e];
}

// ================= aggregation: one wave per (node,type) =================
// X[key][d] = sum over edges of hb[dst][d]; hb lives in Acat cols 256..384
__global__ void agg3(const int* __restrict__ offsets, const int* __restrict__ elist,
                     const __bf16* __restrict__ Acat, __bf16* __restrict__ X) {
    int w = blockIdx.x * 4 + (threadIdx.x >> 6);
    if (w >= NKEY) return;
    int lane = threadIdx.x & 63;
    int beg = offsets[w], end = offsets[w + 1];
    float ax = 0.f, ay = 0.f;
    for (int j = beg; j < end; ++j) {
        int dst = elist[j];
        bf16x2 v = *(const bf16x2*)(Acat + (size_t)dst * 384 + 256 + lane * 2);
        ax += (float)v.x;
        ay += (float)v.y;
    }
    bf16x2 o; o.x = (__bf16)ax; o.y = (__bf16)ay;
    *(bf16x2*)(X + (size_t)w * 128 + lane * 2) = o;
}

// ================= msgs GEMM: Acat[:,0:256] = relu(X @ Wcat + n_t-weighted bias) =================
// block: 64 rows x 256 cols, 4 waves (wave = 16 rows x 256 cols = 16 tiles), K=512 in 16 chunks
__global__ void msgs_gemm2(const __bf16* __restrict__ X, const __bf16* __restrict__ WK,
                           const float* __restrict__ b_msg, const int* __restrict__ offsets,
                           __bf16* __restrict__ Acat) {
    __shared__ __bf16 Bs[8192];   // 16 KB: [lq][col][8]
    int tid = threadIdx.x, wave = tid >> 6, lane = tid & 63;
    int lm = lane & 15, lq = lane >> 4;
    int r0 = blockIdx.x * 64 + wave * 16;
    int arow = r0 + lm; if (arow >= NN) arow = NN - 1;
    const __bf16* Ap = X + (size_t)arow * 512 + lq * 8;

    f32x4 acc[16] = {};
    for (int c = 0; c < 16; ++c) {
        __syncthreads();
        const __bf16* src = WK + (size_t)c * 8192;
#pragma unroll
        for (int i = 0; i < 4; ++i)
            *(bf16x8*)&Bs[(i * 256 + tid) * 8] = *(const bf16x8*)(src + (size_t)(i * 256 + tid) * 8);
        bf16x8 a = *(const bf16x8*)(Ap + c * 32);
        __syncthreads();
#pragma unroll
        for (int nt = 0; nt < 16; ++nt) {
            bf16x8 b = *(const bf16x8*)&Bs[((size_t)lq * 256 + nt * 16 + lm) * 8];
            acc[nt] = __builtin_amdgcn_mfma_f32_16x16x32_bf16(a, b, acc[nt], 0, 0, 0);
        }
    }
#pragma unroll
    for (int i = 0; i < 4; ++i) {
        int row = r0 + lq * 4 + i;
        if (row >= NN) continue;
        int ob = row * TT;
        int o0 = offsets[ob], o1 = offsets[ob + 1], o2 = offsets[ob + 2],
            o3 = offsets[ob + 3], o4 = offsets[ob + 4];
        float n0 = (float)(o1 - o0), n1 = (float)(o2 - o1),
              n2 = (float)(o3 - o2), n3 = (float)(o4 - o3);
#pragma unroll
        for (int nt = 0; nt < 16; ++nt) {
            int col = nt * 16 + lm;
            float bias = n0 * b_msg[col] + n1 * b_msg[MM + col]
                       + n2 * b_msg[2 * MM + col] + n3 * b_msg[3 * MM + col];
            Acat[(size_t)row * 384 + col] = (__bf16)fmaxf(acc[nt][i] + bias, 0.f);
        }
    }
}

// ================= fused GRU GEMM =================
// C(50000 x 512) = Acat(50000 x 384) @ WB^T; cols [r|z|i_n|h_n]; epilogue = GRUCell,
// writes hf (fp32 master) and new hb into Acat[:,256:384]. Wave = 16 rows x 512 cols.
__global__ void gru_gemm(const __bf16* __restrict__ Acat, const __bf16* __restrict__ WB,
                         const float* __restrict__ b512, float* __restrict__ hf) {
    __shared__ __bf16 Bs[16384];  // 32 KB: [lq][col][8]
    int tid = threadIdx.x, wave = tid >> 6, lane = tid & 63;
    int lm = lane & 15, lq = lane >> 4;
    int r0 = blockIdx.x * 64 + wave * 16;
    int arow = r0 + lm; if (arow >= NN) arow = NN - 1;
    const __bf16* Ap = Acat + (size_t)arow * 384 + lq * 8;

    f32x4 acc[32] = {};
    for (int c = 0; c < 12; ++c) {
        __syncthreads();
        const __bf16* src = WB + (size_t)c * 16384;
#pragma unroll
        for (int i = 0; i < 8; ++i)
            *(bf16x8*)&Bs[(i * 256 + tid) * 8] = *(const bf16x8*)(src + (size_t)(i * 256 + tid) * 8);
        bf16x8 a = *(const bf16x8*)(Ap + c * 32);
        __syncthreads();
#pragma unroll
        for (int nt = 0; nt < 32; ++nt) {
            bf16x8 b = *(const bf16x8*)&Bs[((size_t)lq * 512 + nt * 16 + lm) * 8];
            acc[nt] = __builtin_amdgcn_mfma_f32_16x16x32_bf16(a, b, acc[nt], 0, 0, 0);
        }
    }
    __bf16* AcatW = (__bf16*)Acat;
#pragma unroll
    for (int i = 0; i < 4; ++i) {
        int row = r0 + lq * 4 + i;
        if (row >= NN) continue;
#pragma unroll
        for (int j = 0; j < 8; ++j) {
            int d = j * 16 + lm;
            float pr  = acc[j][i]      + b512[d];
            float pz  = acc[8 + j][i]  + b512[128 + d];
            float pin = acc[16 + j][i] + b512[256 + d];
            float phn = acc[24 + j][i] + b512[384 + d];
            float r = 1.f / (1.f + expf(-pr));
            float z = 1.f / (1.f + expf(-pz));
            float nv = tanhf(pin + r * phn);
            float hold = hf[(size_t)row * DD + d];
            float hnew = (1.f - z) * nv + z * hold;
            hf[(size_t)row * DD + d] = hnew;
            AcatW[(size_t)row * 384 + 256 + d] = (__bf16)hnew;
        }
    }
}

// ================= readout =================
__global__ void attn_kernel(const float* __restrict__ hf, const float* __restrict__ w_gate,
                            const float* __restrict__ b_gate, float* __restrict__ attn) {
    int node = blockIdx.x * 4 + (threadIdx.x >> 6);
    int lane = threadIdx.x & 63;
    if (node >= NN) return;
    size_t base = (size_t)node * DD;
    float s = hf[base + lane * 2] * w_gate[lane * 2]
            + hf[base + lane * 2 + 1] * w_gate[lane * 2 + 1];
    for (int off = 32; off; off >>= 1) s += __shfl_down(s, off);
    if (lane == 0) attn[node] = 1.f / (1.f + expf(-(s + b_gate[0])));
}

__global__ void segsum_kernel(const int* __restrict__ goff, const float* __restrict__ attn,
                              const float* __restrict__ hf, float* __restrict__ sg,
                              float* __restrict__ asumg) {
    int g = blockIdx.x;
    int d = threadIdx.x;
    int beg = goff[g], end = goff[g + 1];
    float s = 0.f, asum = 0.f;
    for (int i = beg; i < end; ++i) {
        float a = attn[i];
        s += a * hf[(size_t)i * DD + d];
        if (d == 0) asum += a;
    }
    sg[g * DD + d] = s;
    if (d == 0) asumg[g] = asum;
}

__global__ void readout_kernel(const float* __restrict__ sg, const float* __restrict__ asumg,
                               const float* __restrict__ W_g, const float* __restrict__ b_g,
                               float* __restrict__ hgraph) {
    int g = blockIdx.x;
    int m = threadIdx.x;
    float acc = asumg[g] * b_g[m];
    for (int d = 0; d < DD; ++d) acc += sg[g * DD + d] * W_g[d * GHID + m];
    hgraph[g * GHID + m] = acc;
}

// ================= launch =================
extern "C" void kernel_launch(void* const* d_in, const int* in_sizes, int n_in,
                              void* d_out, int out_size, void* d_ws, size_t ws_size,
                              hipStream_t stream) {
    const int*   node_types = (const int*)d_in[0];
    const int*   edge_src   = (const int*)d_in[1];
    const int*   edge_dst   = (const int*)d_in[2];
    const int*   edge_type  = (const int*)d_in[3];
    const int*   node2graph = (const int*)d_in[4];
    const float* emb        = (const float*)d_in[5];
    const float* W_msg      = (const float*)d_in[6];
    const float* b_msg      = (const float*)d_in[7];
    const float* W_ih       = (const float*)d_in[8];
    const float* W_hh       = (const float*)d_in[9];
    const float* b_ih       = (const float*)d_in[10];
    const float* b_hh       = (const float*)d_in[11];
    const float* w_gate     = (const float*)d_in[12];
    const float* b_gate     = (const float*)d_in[13];
    const float* W_g        = (const float*)d_in[14];
    const float* b_g        = (const float*)d_in[15];

    float* hf     = (float*)d_out;
    float* hgraph = hf + (size_t)NN * DD;

    char* ws = (char*)d_ws;
    size_t off = 0;
    auto alloc = [&](size_t bytes) -> char* {
        char* p = ws + off;
        off += (bytes + 255) & ~(size_t)255;
        return p;
    };
    __bf16* X       = (__bf16*)alloc((size_t)NN * 512 * 2);   // 51.2 MB
    __bf16* Acat    = (__bf16*)alloc((size_t)NN * 384 * 2);   // 38.4 MB  [msgs(256)|hb(128)]
    __bf16* WK      = (__bf16*)alloc((size_t)16 * 4 * 256 * 8 * 2);
    __bf16* WB      = (__bf16*)alloc((size_t)12 * 4 * 512 * 8 * 2);
    float*  b512    = (float*)alloc(512 * 4);
    float*  attn    = (float*)alloc((size_t)NN * 4);
    float*  sg      = (float*)alloc((size_t)NG * DD * 4);
    float*  asumg   = (float*)alloc((size_t)NG * 4);
    int*    counts  = (int*)alloc((size_t)(NKEY + 1) * 4);
    int*    offsets = (int*)alloc((size_t)(NKEY + 1) * 4);
    int*    cursor  = (int*)alloc((size_t)(NKEY + 1) * 4);
    int*    bsum    = (int*)alloc((size_t)1024 * 4);
    int*    elist   = (int*)alloc((size_t)NE * 4);
    int*    gcounts = (int*)alloc((size_t)(NG + 1) * 4);
    int*    goff    = (int*)alloc((size_t)(NG + 1) * 4);
    int*    gbsum   = (int*)alloc((size_t)8 * 4);

    hipMemsetAsync(counts, 0, (NKEY + 1) * 4, stream);
    hipMemsetAsync(gcounts, 0, (NG + 1) * 4, stream);

    build_WK<<<(16 * 4 * 256 * 8 + 255) / 256, 256, 0, stream>>>(W_msg, WK);
    build_WB<<<(12 * 4 * 512 * 8 + 255) / 256, 256, 0, stream>>>(W_ih, W_hh, WB);
    build_bias512<<<2, 256, 0, stream>>>(b_ih, b_hh, b512);
    embed_kernel<<<(NN * DD + 255) / 256, 256, 0, stream>>>(node_types, emb, hf, Acat);

    int nbE = (NKEY + 255) / 256;
    hist_kernel<<<(NE + 255) / 256, 256, 0, stream>>>(edge_src, edge_type, counts);
    scan1<<<nbE, 256, 0, stream>>>(counts, offsets, bsum, NKEY);
    scan2<<<1, 1024, 0, stream>>>(bsum, nbE, offsets, NKEY);
    scan3<<<nbE, 256, 0, stream>>>(offsets, bsum, cursor, NKEY);
    fill_kernel<<<(NE + 255) / 256, 256, 0, stream>>>(edge_src, edge_dst, edge_type, cursor, elist);

    int nbG = (NG + 255) / 256;
    ghist_kernel<<<(NN + 255) / 256, 256, 0, stream>>>(node2graph, gcounts);
    scan1<<<nbG, 256, 0, stream>>>(gcounts, goff, gbsum, NG);
    scan2<<<1, 1024, 0, stream>>>(gbsum, nbG, goff, NG);
    scan3<<<nbG, 256, 0, stream>>>(goff, gbsum, (int*)nullptr, NG);

    int rt = (NN + 63) / 64;  // 782
    for (int p = 0; p < NPASS; ++p) {
        agg3<<<(NKEY + 3) / 4, 256, 0, stream>>>(offsets, elist, Acat, X);
        msgs_gemm2<<<rt, 256, 0, stream>>>(X, WK, b_msg, offsets, Acat);
        gru_gemm<<<rt, 256, 0, stream>>>(Acat, WB, b512, hf);
    }

    attn_kernel<<<(NN + 3) / 4, 256, 0, stream>>>(hf, w_gate, b_gate, attn);
    segsum_kernel<<<NG, 128, 0, stream>>>(goff, attn, hf, sg, asumg);
    readout_kernel<<<NG, GHID, 0, stream>>>(sg, asumg, W_g, b_g, hgraph);
}

// Round 5
// 1056.124 us; speedup vs baseline: 2.1654x; 1.3112x over previous
//
#include <hip/hip_runtime.h>
#include <hip/hip_bf16.h>

#define NN 50000
#define NE 800000
#define NG 512
#define DD 128
#define MM 256
#define TT 4
#define NPASS 4
#define GHID 256
#define NKEY (NN * TT)          // CSR keys: src*4 + type

typedef __bf16 bf16x2 __attribute__((ext_vector_type(2)));
typedef __bf16 bf16x8 __attribute__((ext_vector_type(8)));
typedef float f32x4 __attribute__((ext_vector_type(4)));

// ================= setup: swizzled weights =================
// WK for msgs GEMM (K=512 -> 16 chunks of 32): WK[((c*4+lq)*256+col)*8+j] = W_msg[k*256+col], k=(c*4+lq)*8+j
__global__ void build_WK(const float* __restrict__ W_msg, __bf16* __restrict__ WK) {
    int i = blockIdx.x * 256 + threadIdx.x;           // 131072
    if (i >= 16 * 4 * 256 * 8) return;
    int j = i & 7, col = (i >> 3) & 255, g = i >> 11; // g=c*4+lq
    int k = g * 8 + j;
    WK[i] = (__bf16)W_msg[k * 256 + col];
}

// WB for fused GRU GEMM: 512 cols x K=384 (12 chunks). cols: [0,128)=r pre, [128,256)=z pre
// (Wih+Whh stacked over k), [256,384)=i_n (Wih only), [384,512)=h_n (Whh only).
__global__ void build_WB(const float* __restrict__ W_ih, const float* __restrict__ W_hh,
                         __bf16* __restrict__ WB) {
    int i = blockIdx.x * 256 + threadIdx.x;           // 196608
    if (i >= 12 * 4 * 512 * 8) return;
    int j = i & 7, col = (i >> 3) & 511, g = i >> 12; // g=c*4+lq
    int k = g * 8 + j;                                // 0..383
    float v = 0.f;
    if (col < 256) {
        v = (k < 256) ? W_ih[col * 256 + k] : W_hh[col * 128 + (k - 256)];
    } else if (col < 384) {
        if (k < 256) v = W_ih[col * 256 + k];
    } else {
        if (k >= 256) v = W_hh[(col - 128) * 128 + (k - 256)];
    }
    WB[i] = (__bf16)v;
}

__global__ void build_bias512(const float* __restrict__ b_ih, const float* __restrict__ b_hh,
                              float* __restrict__ b512) {
    int c = blockIdx.x * 256 + threadIdx.x;
    if (c >= 512) return;
    float v;
    if (c < 256) v = b_ih[c] + b_hh[c];
    else if (c < 384) v = b_ih[c];
    else v = b_hh[c - 128];
    b512[c] = v;
}

// ================= embedding =================
__global__ void embed_kernel(const int* __restrict__ node_types,
                             const float* __restrict__ emb,
                             float* __restrict__ hf, __bf16* __restrict__ Acat) {
    int t = blockIdx.x * 256 + threadIdx.x;
    if (t >= NN * DD) return;
    int node = t >> 7, d = t & 127;
    float v = emb[node_types[node] * DD + d];
    hf[t] = v;
    Acat[(size_t)node * 384 + 256 + d] = (__bf16)v;
}

// ================= CSR build (keyed by src*4+type) =================
__global__ void hist_kernel(const int* __restrict__ src, const int* __restrict__ et,
                            int* __restrict__ counts) {
    int e = blockIdx.x * 256 + threadIdx.x;
    if (e < NE) atomicAdd(&counts[src[e] * TT + et[e]], 1);
}

__global__ void ghist_kernel(const int* __restrict__ n2g, int* __restrict__ gcounts) {
    int i = blockIdx.x * 256 + threadIdx.x;
    if (i < NN) atomicAdd(&gcounts[n2g[i]], 1);
}

__global__ void scan1(const int* __restrict__ counts, int* __restrict__ offsets,
                      int* __restrict__ bsum, int n) {
    __shared__ int sm[256];
    int i = blockIdx.x * 256 + threadIdx.x;
    int v = (i < n) ? counts[i] : 0;
    sm[threadIdx.x] = v;
    __syncthreads();
    for (int off = 1; off < 256; off <<= 1) {
        int t = (threadIdx.x >= off) ? sm[threadIdx.x - off] : 0;
        __syncthreads();
        sm[threadIdx.x] += t;
        __syncthreads();
    }
    if (i < n) offsets[i] = sm[threadIdx.x] - v;
    if (threadIdx.x == 255) bsum[blockIdx.x] = sm[255];
}

__global__ void scan2(int* __restrict__ bsum, int nb, int* __restrict__ offsets, int n) {
    __shared__ int sm[1024];
    int v = (threadIdx.x < nb) ? bsum[threadIdx.x] : 0;
    sm[threadIdx.x] = v;
    __syncthreads();
    for (int off = 1; off < 1024; off <<= 1) {
        int t = (threadIdx.x >= off) ? sm[threadIdx.x - off] : 0;
        __syncthreads();
        sm[threadIdx.x] += t;
        __syncthreads();
    }
    if (threadIdx.x < nb) bsum[threadIdx.x] = sm[threadIdx.x] - v;
    if (threadIdx.x == 1023) offsets[n] = sm[1023];
}

__global__ void scan3(int* __restrict__ offsets, const int* __restrict__ bsum,
                      int* __restrict__ cursor, int n) {
    int i = blockIdx.x * 256 + threadIdx.x;
    if (i < n) {
        int o = offsets[i] + bsum[blockIdx.x];
        offsets[i] = o;
        if (cursor) cursor[i] = o;
    }
}

__global__ void fill_kernel(const int* __restrict__ src, const int* __restrict__ dst,
                            const int* __restrict__ et, int* __restrict__ cursor,
                            int* __restrict__ elist) {
    int e = blockIdx.x * 256 + threadIdx.x;
    if (e >= NE) return;
    int pos = atomicAdd(&cursor[src[e] * TT + et[e]], 1);
    elist[pos] = dst[e];
}

// ================= aggregation: one wave per (node,type) =================
__global__ void agg3(const int* __restrict__ offsets, const int* __restrict__ elist,
                     const __bf16* __restrict__ Acat, __bf16* __restrict__ X) {
    int w = blockIdx.x * 4 + (threadIdx.x >> 6);
    if (w >= NKEY) return;
    int lane = threadIdx.x & 63;
    int beg = offsets[w], end = offsets[w + 1];
    float ax = 0.f, ay = 0.f;
    for (int j = beg; j < end; ++j) {
        int dst = elist[j];
        bf16x2 v = *(const bf16x2*)(Acat + (size_t)dst * 384 + 256 + lane * 2);
        ax += (float)v.x;
        ay += (float)v.y;
    }
    bf16x2 o; o.x = (__bf16)ax; o.y = (__bf16)ay;
    *(bf16x2*)(X + (size_t)w * 128 + lane * 2) = o;
}

// ================= msgs GEMM: Acat[:,0:256] = relu(X @ Wcat + n_t-weighted bias) =================
// block: 64 rows x 256 cols, 4 waves (wave = 16 rows x 256 cols = 16 tiles), K=512 in 16 chunks
__global__ void msgs_gemm2(const __bf16* __restrict__ X, const __bf16* __restrict__ WK,
                           const float* __restrict__ b_msg, const int* __restrict__ offsets,
                           __bf16* __restrict__ Acat) {
    __shared__ __bf16 Bs[8192];   // 16 KB: [lq][col][8]
    int tid = threadIdx.x, wave = tid >> 6, lane = tid & 63;
    int lm = lane & 15, lq = lane >> 4;
    int r0 = blockIdx.x * 64 + wave * 16;
    int arow = r0 + lm; if (arow >= NN) arow = NN - 1;
    const __bf16* Ap = X + (size_t)arow * 512 + lq * 8;

    f32x4 acc[16] = {};
    for (int c = 0; c < 16; ++c) {
        __syncthreads();
        const __bf16* src = WK + (size_t)c * 8192;
#pragma unroll
        for (int i = 0; i < 4; ++i)
            *(bf16x8*)&Bs[(i * 256 + tid) * 8] = *(const bf16x8*)(src + (size_t)(i * 256 + tid) * 8);
        bf16x8 a = *(const bf16x8*)(Ap + c * 32);
        __syncthreads();
#pragma unroll
        for (int nt = 0; nt < 16; ++nt) {
            bf16x8 b = *(const bf16x8*)&Bs[((size_t)lq * 256 + nt * 16 + lm) * 8];
            acc[nt] = __builtin_amdgcn_mfma_f32_16x16x32_bf16(a, b, acc[nt], 0, 0, 0);
        }
    }
#pragma unroll
    for (int i = 0; i < 4; ++i) {
        int row = r0 + lq * 4 + i;
        if (row >= NN) continue;
        int ob = row * TT;
        int o0 = offsets[ob], o1 = offsets[ob + 1], o2 = offsets[ob + 2],
            o3 = offsets[ob + 3], o4 = offsets[ob + 4];
        float n0 = (float)(o1 - o0), n1 = (float)(o2 - o1),
              n2 = (float)(o3 - o2), n3 = (float)(o4 - o3);
#pragma unroll
        for (int nt = 0; nt < 16; ++nt) {
            int col = nt * 16 + lm;
            float bias = n0 * b_msg[col] + n1 * b_msg[MM + col]
                       + n2 * b_msg[2 * MM + col] + n3 * b_msg[3 * MM + col];
            Acat[(size_t)row * 384 + col] = (__bf16)fmaxf(acc[nt][i] + bias, 0.f);
        }
    }
}

// ================= fused GRU GEMM (low-register restructure) =================
// Wave = 16 rows. A row-fragment (K=384, 12 chunks) held in registers.
// Loop 8 gate-column groups j; per group only 4 accumulators (r,z,i_n,h_n) live;
// B fragments read directly from swizzled WB (L2-resident); GRU epilogue per group.
__global__ void gru_gemm(const __bf16* __restrict__ Acat, const __bf16* __restrict__ WB,
                         const float* __restrict__ b512, float* __restrict__ hf) {
    int tid = threadIdx.x, wave = tid >> 6, lane = tid & 63;
    int lm = lane & 15, lq = lane >> 4;
    int r0 = blockIdx.x * 64 + wave * 16;
    int arow = r0 + lm; if (arow >= NN) arow = NN - 1;
    const __bf16* Ap = Acat + (size_t)arow * 384 + lq * 8;

    bf16x8 a[12];
#pragma unroll
    for (int c = 0; c < 12; ++c) a[c] = *(const bf16x8*)(Ap + c * 32);

    __bf16* AcatW = const_cast<__bf16*>(Acat);
#pragma unroll
    for (int j = 0; j < 8; ++j) {
        f32x4 ar = {}, az = {}, an = {}, ah = {};
        const __bf16* Bj = WB + ((size_t)lq * 512 + j * 16 + lm) * 8;
#pragma unroll
        for (int c = 0; c < 12; ++c) {
            const __bf16* Bp = Bj + (size_t)c * 4 * 512 * 8;
            bf16x8 br = *(const bf16x8*)(Bp);
            bf16x8 bz = *(const bf16x8*)(Bp + 128 * 8);
            bf16x8 bn = *(const bf16x8*)(Bp + 256 * 8);
            bf16x8 bh = *(const bf16x8*)(Bp + 384 * 8);
            ar = __builtin_amdgcn_mfma_f32_16x16x32_bf16(a[c], br, ar, 0, 0, 0);
            az = __builtin_amdgcn_mfma_f32_16x16x32_bf16(a[c], bz, az, 0, 0, 0);
            an = __builtin_amdgcn_mfma_f32_16x16x32_bf16(a[c], bn, an, 0, 0, 0);
            ah = __builtin_amdgcn_mfma_f32_16x16x32_bf16(a[c], bh, ah, 0, 0, 0);
        }
        int d = j * 16 + lm;
        float cbr = b512[d], cbz = b512[128 + d], cbn = b512[256 + d], cbh = b512[384 + d];
#pragma unroll
        for (int i = 0; i < 4; ++i) {
            int row = r0 + lq * 4 + i;
            if (row >= NN) continue;
            float pr  = ar[i] + cbr;
            float pz  = az[i] + cbz;
            float pin = an[i] + cbn;
            float phn = ah[i] + cbh;
            float r = 1.f / (1.f + expf(-pr));
            float z = 1.f / (1.f + expf(-pz));
            float nv = tanhf(pin + r * phn);
            float hold = hf[(size_t)row * DD + d];
            float hnew = (1.f - z) * nv + z * hold;
            hf[(size_t)row * DD + d] = hnew;
            AcatW[(size_t)row * 384 + 256 + d] = (__bf16)hnew;
        }
    }
}

// ================= readout =================
__global__ void attn_kernel(const float* __restrict__ hf, const float* __restrict__ w_gate,
                            const float* __restrict__ b_gate, float* __restrict__ attn) {
    int node = blockIdx.x * 4 + (threadIdx.x >> 6);
    int lane = threadIdx.x & 63;
    if (node >= NN) return;
    size_t base = (size_t)node * DD;
    float s = hf[base + lane * 2] * w_gate[lane * 2]
            + hf[base + lane * 2 + 1] * w_gate[lane * 2 + 1];
    for (int off = 32; off; off >>= 1) s += __shfl_down(s, off);
    if (lane == 0) attn[node] = 1.f / (1.f + expf(-(s + b_gate[0])));
}

__global__ void segsum_kernel(const int* __restrict__ goff, const float* __restrict__ attn,
                              const float* __restrict__ hf, float* __restrict__ sg,
                              float* __restrict__ asumg) {
    int g = blockIdx.x;
    int d = threadIdx.x;
    int beg = goff[g], end = goff[g + 1];
    float s = 0.f, asum = 0.f;
    for (int i = beg; i < end; ++i) {
        float a = attn[i];
        s += a * hf[(size_t)i * DD + d];
        if (d == 0) asum += a;
    }
    sg[g * DD + d] = s;
    if (d == 0) asumg[g] = asum;
}

__global__ void readout_kernel(const float* __restrict__ sg, const float* __restrict__ asumg,
                               const float* __restrict__ W_g, const float* __restrict__ b_g,
                               float* __restrict__ hgraph) {
    int g = blockIdx.x;
    int m = threadIdx.x;
    float acc = asumg[g] * b_g[m];
    for (int d = 0; d < DD; ++d) acc += sg[g * DD + d] * W_g[d * GHID + m];
    hgraph[g * GHID + m] = acc;
}

// ================= launch =================
extern "C" void kernel_launch(void* const* d_in, const int* in_sizes, int n_in,
                              void* d_out, int out_size, void* d_ws, size_t ws_size,
                              hipStream_t stream) {
    const int*   node_types = (const int*)d_in[0];
    const int*   edge_src   = (const int*)d_in[1];
    const int*   edge_dst   = (const int*)d_in[2];
    const int*   edge_type  = (const int*)d_in[3];
    const int*   node2graph = (const int*)d_in[4];
    const float* emb        = (const float*)d_in[5];
    const float* W_msg      = (const float*)d_in[6];
    const float* b_msg      = (const float*)d_in[7];
    const float* W_ih       = (const float*)d_in[8];
    const float* W_hh       = (const float*)d_in[9];
    const float* b_ih       = (const float*)d_in[10];
    const float* b_hh       = (const float*)d_in[11];
    const float* w_gate     = (const float*)d_in[12];
    const float* b_gate     = (const float*)d_in[13];
    const float* W_g        = (const float*)d_in[14];
    const float* b_g        = (const float*)d_in[15];

    float* hf     = (float*)d_out;
    float* hgraph = hf + (size_t)NN * DD;

    char* ws = (char*)d_ws;
    size_t off = 0;
    auto alloc = [&](size_t bytes) -> char* {
        char* p = ws + off;
        off += (bytes + 255) & ~(size_t)255;
        return p;
    };
    __bf16* X       = (__bf16*)alloc((size_t)NN * 512 * 2);   // 51.2 MB
    __bf16* Acat    = (__bf16*)alloc((size_t)NN * 384 * 2);   // 38.4 MB  [msgs(256)|hb(128)]
    __bf16* WK      = (__bf16*)alloc((size_t)16 * 4 * 256 * 8 * 2);
    __bf16* WB      = (__bf16*)alloc((size_t)12 * 4 * 512 * 8 * 2);
    float*  b512    = (float*)alloc(512 * 4);
    float*  attn    = (float*)alloc((size_t)NN * 4);
    float*  sg      = (float*)alloc((size_t)NG * DD * 4);
    float*  asumg   = (float*)alloc((size_t)NG * 4);
    int*    counts  = (int*)alloc((size_t)(NKEY + 1) * 4);
    int*    offsets = (int*)alloc((size_t)(NKEY + 1) * 4);
    int*    cursor  = (int*)alloc((size_t)(NKEY + 1) * 4);
    int*    bsum    = (int*)alloc((size_t)1024 * 4);
    int*    elist   = (int*)alloc((size_t)NE * 4);
    int*    gcounts = (int*)alloc((size_t)(NG + 1) * 4);
    int*    goff    = (int*)alloc((size_t)(NG + 1) * 4);
    int*    gbsum   = (int*)alloc((size_t)8 * 4);

    hipMemsetAsync(counts, 0, (NKEY + 1) * 4, stream);
    hipMemsetAsync(gcounts, 0, (NG + 1) * 4, stream);

    build_WK<<<(16 * 4 * 256 * 8 + 255) / 256, 256, 0, stream>>>(W_msg, WK);
    build_WB<<<(12 * 4 * 512 * 8 + 255) / 256, 256, 0, stream>>>(W_ih, W_hh, WB);
    build_bias512<<<2, 256, 0, stream>>>(b_ih, b_hh, b512);
    embed_kernel<<<(NN * DD + 255) / 256, 256, 0, stream>>>(node_types, emb, hf, Acat);

    int nbE = (NKEY + 255) / 256;
    hist_kernel<<<(NE + 255) / 256, 256, 0, stream>>>(edge_src, edge_type, counts);
    scan1<<<nbE, 256, 0, stream>>>(counts, offsets, bsum, NKEY);
    scan2<<<1, 1024, 0, stream>>>(bsum, nbE, offsets, NKEY);
    scan3<<<nbE, 256, 0, stream>>>(offsets, bsum, cursor, NKEY);
    fill_kernel<<<(NE + 255) / 256, 256, 0, stream>>>(edge_src, edge_dst, edge_type, cursor, elist);

    int nbG = (NG + 255) / 256;
    ghist_kernel<<<(NN + 255) / 256, 256, 0, stream>>>(node2graph, gcounts);
    scan1<<<nbG, 256, 0, stream>>>(gcounts, goff, gbsum, NG);
    scan2<<<1, 1024, 0, stream>>>(gbsum, nbG, goff, NG);
    scan3<<<nbG, 256, 0, stream>>>(goff, gbsum, (int*)nullptr, NG);

    int rt = (NN + 63) / 64;  // 782
    for (int p = 0; p < NPASS; ++p) {
        agg3<<<(NKEY + 3) / 4, 256, 0, stream>>>(offsets, elist, Acat, X);
        msgs_gemm2<<<rt, 256, 0, stream>>>(X, WK, b_msg, offsets, Acat);
        gru_gemm<<<rt, 256, 0, stream>>>(Acat, WB, b512, hf);
    }

    attn_kernel<<<(NN + 3) / 4, 256, 0, stream>>>(hf, w_gate, b_gate, attn);
    segsum_kernel<<<NG, 128, 0, stream>>>(goff, attn, hf, sg, asumg);
    readout_kernel<<<NG, GHID, 0, stream>>>(sg, asumg, W_g, b_g, hgraph);
}

// Round 6
// 894.152 us; speedup vs baseline: 2.5577x; 1.1811x over previous
//
#include <hip/hip_runtime.h>
#include <hip/hip_bf16.h>

#define NN 50000
#define NE 800000
#define NG 512
#define DD 128
#define MM 256
#define TT 4
#define NPASS 4
#define GHID 256
#define NKEY (NN * TT)          // CSR keys: src*4 + type

typedef __bf16 bf16x2 __attribute__((ext_vector_type(2)));
typedef __bf16 bf16x8 __attribute__((ext_vector_type(8)));
typedef float f32x4 __attribute__((ext_vector_type(4)));

// ================= setup: swizzled weights =================
__global__ void build_WK(const float* __restrict__ W_msg, __bf16* __restrict__ WK) {
    int i = blockIdx.x * 256 + threadIdx.x;           // 131072
    if (i >= 16 * 4 * 256 * 8) return;
    int j = i & 7, col = (i >> 3) & 255, g = i >> 11; // g=c*4+lq
    int k = g * 8 + j;
    WK[i] = (__bf16)W_msg[k * 256 + col];
}

__global__ void build_WB(const float* __restrict__ W_ih, const float* __restrict__ W_hh,
                         __bf16* __restrict__ WB) {
    int i = blockIdx.x * 256 + threadIdx.x;           // 196608
    if (i >= 12 * 4 * 512 * 8) return;
    int j = i & 7, col = (i >> 3) & 511, g = i >> 12; // g=c*4+lq
    int k = g * 8 + j;                                // 0..383
    float v = 0.f;
    if (col < 256) {
        v = (k < 256) ? W_ih[col * 256 + k] : W_hh[col * 128 + (k - 256)];
    } else if (col < 384) {
        if (k < 256) v = W_ih[col * 256 + k];
    } else {
        if (k >= 256) v = W_hh[(col - 128) * 128 + (k - 256)];
    }
    WB[i] = (__bf16)v;
}

__global__ void build_bias512(const float* __restrict__ b_ih, const float* __restrict__ b_hh,
                              float* __restrict__ b512) {
    int c = blockIdx.x * 256 + threadIdx.x;
    if (c >= 512) return;
    float v;
    if (c < 256) v = b_ih[c] + b_hh[c];
    else if (c < 384) v = b_ih[c];
    else v = b_hh[c - 128];
    b512[c] = v;
}

// ================= embedding =================
__global__ void embed_kernel(const int* __restrict__ node_types,
                             const float* __restrict__ emb,
                             float* __restrict__ hf, __bf16* __restrict__ Acat) {
    int t = blockIdx.x * 256 + threadIdx.x;
    if (t >= NN * DD) return;
    int node = t >> 7, d = t & 127;
    float v = emb[node_types[node] * DD + d];
    hf[t] = v;
    Acat[(size_t)node * 384 + 256 + d] = (__bf16)v;
}

// ================= CSR build (keyed by src*4+type) =================
__global__ void hist_kernel(const int* __restrict__ src, const int* __restrict__ et,
                            int* __restrict__ counts) {
    int e = blockIdx.x * 256 + threadIdx.x;
    if (e < NE) atomicAdd(&counts[src[e] * TT + et[e]], 1);
}

__global__ void ghist_kernel(const int* __restrict__ n2g, int* __restrict__ gcounts) {
    int i = blockIdx.x * 256 + threadIdx.x;
    if (i < NN) atomicAdd(&gcounts[n2g[i]], 1);
}

__global__ void scan1(const int* __restrict__ counts, int* __restrict__ offsets,
                      int* __restrict__ bsum, int n) {
    __shared__ int sm[256];
    int i = blockIdx.x * 256 + threadIdx.x;
    int v = (i < n) ? counts[i] : 0;
    sm[threadIdx.x] = v;
    __syncthreads();
    for (int off = 1; off < 256; off <<= 1) {
        int t = (threadIdx.x >= off) ? sm[threadIdx.x - off] : 0;
        __syncthreads();
        sm[threadIdx.x] += t;
        __syncthreads();
    }
    if (i < n) offsets[i] = sm[threadIdx.x] - v;
    if (threadIdx.x == 255) bsum[blockIdx.x] = sm[255];
}

__global__ void scan2(int* __restrict__ bsum, int nb, int* __restrict__ offsets, int n) {
    __shared__ int sm[1024];
    int v = (threadIdx.x < nb) ? bsum[threadIdx.x] : 0;
    sm[threadIdx.x] = v;
    __syncthreads();
    for (int off = 1; off < 1024; off <<= 1) {
        int t = (threadIdx.x >= off) ? sm[threadIdx.x - off] : 0;
        __syncthreads();
        sm[threadIdx.x] += t;
        __syncthreads();
    }
    if (threadIdx.x < nb) bsum[threadIdx.x] = sm[threadIdx.x] - v;
    if (threadIdx.x == 1023) offsets[n] = sm[1023];
}

__global__ void scan3(int* __restrict__ offsets, const int* __restrict__ bsum,
                      int* __restrict__ cursor, int n) {
    int i = blockIdx.x * 256 + threadIdx.x;
    if (i < n) {
        int o = offsets[i] + bsum[blockIdx.x];
        offsets[i] = o;
        if (cursor) cursor[i] = o;
    }
}

__global__ void fill_kernel(const int* __restrict__ src, const int* __restrict__ dst,
                            const int* __restrict__ et, int* __restrict__ cursor,
                            int* __restrict__ elist) {
    int e = blockIdx.x * 256 + threadIdx.x;
    if (e >= NE) return;
    int pos = atomicAdd(&cursor[src[e] * TT + et[e]], 1);
    elist[pos] = dst[e];
}

// ================= aggregation: wave per key, 8 concurrent gathers =================
// X[key][d] = sum over edges of hb[dst][d]; hb lives in Acat cols 256..384
__global__ void agg4(const int* __restrict__ offsets, const int* __restrict__ elist,
                     const __bf16* __restrict__ Acat, __bf16* __restrict__ X) {
    int w = blockIdx.x * 4 + (threadIdx.x >> 6);
    if (w >= NKEY) return;
    int lane = threadIdx.x & 63;
    int beg = offsets[w], end = offsets[w + 1];
    float ax = 0.f, ay = 0.f;
    for (int base = beg; base < end; base += 8) {
        int nb = end - base; if (nb > 8) nb = 8;          // wave-uniform
        int idx = (lane < nb) ? elist[base + lane] : 0;   // one vector load for <=8 indices
        int i0 = __shfl(idx, 0), i1 = __shfl(idx, 1), i2 = __shfl(idx, 2), i3 = __shfl(idx, 3);
        int i4 = __shfl(idx, 4), i5 = __shfl(idx, 5), i6 = __shfl(idx, 6), i7 = __shfl(idx, 7);
        size_t col = 256 + lane * 2;
        // uniform branches; loads issue back-to-back and overlap in the vm queue
        bf16x2 v0, v1, v2, v3, v4, v5, v6, v7;
        v0 = *(const bf16x2*)(Acat + (size_t)i0 * 384 + col);
        if (nb > 1) v1 = *(const bf16x2*)(Acat + (size_t)i1 * 384 + col);
        if (nb > 2) v2 = *(const bf16x2*)(Acat + (size_t)i2 * 384 + col);
        if (nb > 3) v3 = *(const bf16x2*)(Acat + (size_t)i3 * 384 + col);
        if (nb > 4) v4 = *(const bf16x2*)(Acat + (size_t)i4 * 384 + col);
        if (nb > 5) v5 = *(const bf16x2*)(Acat + (size_t)i5 * 384 + col);
        if (nb > 6) v6 = *(const bf16x2*)(Acat + (size_t)i6 * 384 + col);
        if (nb > 7) v7 = *(const bf16x2*)(Acat + (size_t)i7 * 384 + col);
        ax += (float)v0.x; ay += (float)v0.y;
        if (nb > 1) { ax += (float)v1.x; ay += (float)v1.y; }
        if (nb > 2) { ax += (float)v2.x; ay += (float)v2.y; }
        if (nb > 3) { ax += (float)v3.x; ay += (float)v3.y; }
        if (nb > 4) { ax += (float)v4.x; ay += (float)v4.y; }
        if (nb > 5) { ax += (float)v5.x; ay += (float)v5.y; }
        if (nb > 6) { ax += (float)v6.x; ay += (float)v6.y; }
        if (nb > 7) { ax += (float)v7.x; ay += (float)v7.y; }
    }
    bf16x2 o; o.x = (__bf16)ax; o.y = (__bf16)ay;
    *(bf16x2*)(X + (size_t)w * 128 + lane * 2) = o;
}

// ================= msgs GEMM: Acat[:,0:256] = relu(X @ Wcat + n_t-weighted bias) =================
__global__ void msgs_gemm2(const __bf16* __restrict__ X, const __bf16* __restrict__ WK,
                           const float* __restrict__ b_msg, const int* __restrict__ offsets,
                           __bf16* __restrict__ Acat) {
    __shared__ __bf16 Bs[8192];   // 16 KB: [lq][col][8]
    int tid = threadIdx.x, wave = tid >> 6, lane = tid & 63;
    int lm = lane & 15, lq = lane >> 4;
    int r0 = blockIdx.x * 64 + wave * 16;
    int arow = r0 + lm; if (arow >= NN) arow = NN - 1;
    const __bf16* Ap = X + (size_t)arow * 512 + lq * 8;

    f32x4 acc[16] = {};
    for (int c = 0; c < 16; ++c) {
        __syncthreads();
        const __bf16* src = WK + (size_t)c * 8192;
#pragma unroll
        for (int i = 0; i < 4; ++i)
            *(bf16x8*)&Bs[(i * 256 + tid) * 8] = *(const bf16x8*)(src + (size_t)(i * 256 + tid) * 8);
        bf16x8 a = *(const bf16x8*)(Ap + c * 32);
        __syncthreads();
#pragma unroll
        for (int nt = 0; nt < 16; ++nt) {
            bf16x8 b = *(const bf16x8*)&Bs[((size_t)lq * 256 + nt * 16 + lm) * 8];
            acc[nt] = __builtin_amdgcn_mfma_f32_16x16x32_bf16(a, b, acc[nt], 0, 0, 0);
        }
    }
#pragma unroll
    for (int i = 0; i < 4; ++i) {
        int row = r0 + lq * 4 + i;
        if (row >= NN) continue;
        int ob = row * TT;
        int o0 = offsets[ob], o1 = offsets[ob + 1], o2 = offsets[ob + 2],
            o3 = offsets[ob + 3], o4 = offsets[ob + 4];
        float n0 = (float)(o1 - o0), n1 = (float)(o2 - o1),
              n2 = (float)(o3 - o2), n3 = (float)(o4 - o3);
#pragma unroll
        for (int nt = 0; nt < 16; ++nt) {
            int col = nt * 16 + lm;
            float bias = n0 * b_msg[col] + n1 * b_msg[MM + col]
                       + n2 * b_msg[2 * MM + col] + n3 * b_msg[3 * MM + col];
            Acat[(size_t)row * 384 + col] = (__bf16)fmaxf(acc[nt][i] + bias, 0.f);
        }
    }
}

// ================= fused GRU GEMM (low-register) =================
__global__ void gru_gemm(const __bf16* __restrict__ Acat, const __bf16* __restrict__ WB,
                         const float* __restrict__ b512, float* __restrict__ hf) {
    int tid = threadIdx.x, wave = tid >> 6, lane = tid & 63;
    int lm = lane & 15, lq = lane >> 4;
    int r0 = blockIdx.x * 64 + wave * 16;
    int arow = r0 + lm; if (arow >= NN) arow = NN - 1;
    const __bf16* Ap = Acat + (size_t)arow * 384 + lq * 8;

    bf16x8 a[12];
#pragma unroll
    for (int c = 0; c < 12; ++c) a[c] = *(const bf16x8*)(Ap + c * 32);

    __bf16* AcatW = const_cast<__bf16*>(Acat);
#pragma unroll
    for (int j = 0; j < 8; ++j) {
        f32x4 ar = {}, az = {}, an = {}, ah = {};
        const __bf16* Bj = WB + ((size_t)lq * 512 + j * 16 + lm) * 8;
#pragma unroll
        for (int c = 0; c < 12; ++c) {
            const __bf16* Bp = Bj + (size_t)c * 4 * 512 * 8;
            bf16x8 br = *(const bf16x8*)(Bp);
            bf16x8 bz = *(const bf16x8*)(Bp + 128 * 8);
            bf16x8 bn = *(const bf16x8*)(Bp + 256 * 8);
            bf16x8 bh = *(const bf16x8*)(Bp + 384 * 8);
            ar = __builtin_amdgcn_mfma_f32_16x16x32_bf16(a[c], br, ar, 0, 0, 0);
            az = __builtin_amdgcn_mfma_f32_16x16x32_bf16(a[c], bz, az, 0, 0, 0);
            an = __builtin_amdgcn_mfma_f32_16x16x32_bf16(a[c], bn, an, 0, 0, 0);
            ah = __builtin_amdgcn_mfma_f32_16x16x32_bf16(a[c], bh, ah, 0, 0, 0);
        }
        int d = j * 16 + lm;
        float cbr = b512[d], cbz = b512[128 + d], cbn = b512[256 + d], cbh = b512[384 + d];
#pragma unroll
        for (int i = 0; i < 4; ++i) {
            int row = r0 + lq * 4 + i;
            if (row >= NN) continue;
            float pr  = ar[i] + cbr;
            float pz  = az[i] + cbz;
            float pin = an[i] + cbn;
            float phn = ah[i] + cbh;
            float r = 1.f / (1.f + expf(-pr));
            float z = 1.f / (1.f + expf(-pz));
            float nv = tanhf(pin + r * phn);
            float hold = hf[(size_t)row * DD + d];
            float hnew = (1.f - z) * nv + z * hold;
            hf[(size_t)row * DD + d] = hnew;
            AcatW[(size_t)row * 384 + 256 + d] = (__bf16)hnew;
        }
    }
}

// ================= readout =================
__global__ void attn_kernel(const float* __restrict__ hf, const float* __restrict__ w_gate,
                            const float* __restrict__ b_gate, float* __restrict__ attn) {
    int node = blockIdx.x * 4 + (threadIdx.x >> 6);
    int lane = threadIdx.x & 63;
    if (node >= NN) return;
    size_t base = (size_t)node * DD;
    float s = hf[base + lane * 2] * w_gate[lane * 2]
            + hf[base + lane * 2 + 1] * w_gate[lane * 2 + 1];
    for (int off = 32; off; off >>= 1) s += __shfl_down(s, off);
    if (lane == 0) attn[node] = 1.f / (1.f + expf(-(s + b_gate[0])));
}

__global__ void segsum_kernel(const int* __restrict__ goff, const float* __restrict__ attn,
                              const float* __restrict__ hf, float* __restrict__ sg,
                              float* __restrict__ asumg) {
    int g = blockIdx.x;
    int d = threadIdx.x;
    int beg = goff[g], end = goff[g + 1];
    float s = 0.f, asum = 0.f;
    for (int i = beg; i < end; ++i) {
        float a = attn[i];
        s += a * hf[(size_t)i * DD + d];
        if (d == 0) asum += a;
    }
    sg[g * DD + d] = s;
    if (d == 0) asumg[g] = asum;
}

__global__ void readout_kernel(const float* __restrict__ sg, const float* __restrict__ asumg,
                               const float* __restrict__ W_g, const float* __restrict__ b_g,
                               float* __restrict__ hgraph) {
    int g = blockIdx.x;
    int m = threadIdx.x;
    float acc = asumg[g] * b_g[m];
    for (int d = 0; d < DD; ++d) acc += sg[g * DD + d] * W_g[d * GHID + m];
    hgraph[g * GHID + m] = acc;
}

// ================= launch =================
extern "C" void kernel_launch(void* const* d_in, const int* in_sizes, int n_in,
                              void* d_out, int out_size, void* d_ws, size_t ws_size,
                              hipStream_t stream) {
    const int*   node_types = (const int*)d_in[0];
    const int*   edge_src   = (const int*)d_in[1];
    const int*   edge_dst   = (const int*)d_in[2];
    const int*   edge_type  = (const int*)d_in[3];
    const int*   node2graph = (const int*)d_in[4];
    const float* emb        = (const float*)d_in[5];
    const float* W_msg      = (const float*)d_in[6];
    const float* b_msg      = (const float*)d_in[7];
    const float* W_ih       = (const float*)d_in[8];
    const float* W_hh       = (const float*)d_in[9];
    const float* b_ih       = (const float*)d_in[10];
    const float* b_hh       = (const float*)d_in[11];
    const float* w_gate     = (const float*)d_in[12];
    const float* b_gate     = (const float*)d_in[13];
    const float* W_g        = (const float*)d_in[14];
    const float* b_g        = (const float*)d_in[15];

    float* hf     = (float*)d_out;
    float* hgraph = hf + (size_t)NN * DD;

    char* ws = (char*)d_ws;
    size_t off = 0;
    auto alloc = [&](size_t bytes) -> char* {
        char* p = ws + off;
        off += (bytes + 255) & ~(size_t)255;
        return p;
    };
    __bf16* X       = (__bf16*)alloc((size_t)NN * 512 * 2);   // 51.2 MB
    __bf16* Acat    = (__bf16*)alloc((size_t)NN * 384 * 2);   // 38.4 MB  [msgs(256)|hb(128)]
    __bf16* WK      = (__bf16*)alloc((size_t)16 * 4 * 256 * 8 * 2);
    __bf16* WB      = (__bf16*)alloc((size_t)12 * 4 * 512 * 8 * 2);
    float*  b512    = (float*)alloc(512 * 4);
    float*  attn    = (float*)alloc((size_t)NN * 4);
    float*  sg      = (float*)alloc((size_t)NG * DD * 4);
    float*  asumg   = (float*)alloc((size_t)NG * 4);
    int*    counts  = (int*)alloc((size_t)(NKEY + 1) * 4);
    int*    offsets = (int*)alloc((size_t)(NKEY + 1) * 4);
    int*    cursor  = (int*)alloc((size_t)(NKEY + 1) * 4);
    int*    bsum    = (int*)alloc((size_t)1024 * 4);
    int*    elist   = (int*)alloc((size_t)NE * 4);
    int*    gcounts = (int*)alloc((size_t)(NG + 1) * 4);
    int*    goff    = (int*)alloc((size_t)(NG + 1) * 4);
    int*    gbsum   = (int*)alloc((size_t)8 * 4);

    hipMemsetAsync(counts, 0, (NKEY + 1) * 4, stream);
    hipMemsetAsync(gcounts, 0, (NG + 1) * 4, stream);

    build_WK<<<(16 * 4 * 256 * 8 + 255) / 256, 256, 0, stream>>>(W_msg, WK);
    build_WB<<<(12 * 4 * 512 * 8 + 255) / 256, 256, 0, stream>>>(W_ih, W_hh, WB);
    build_bias512<<<2, 256, 0, stream>>>(b_ih, b_hh, b512);
    embed_kernel<<<(NN * DD + 255) / 256, 256, 0, stream>>>(node_types, emb, hf, Acat);

    int nbE = (NKEY + 255) / 256;
    hist_kernel<<<(NE + 255) / 256, 256, 0, stream>>>(edge_src, edge_type, counts);
    scan1<<<nbE, 256, 0, stream>>>(counts, offsets, bsum, NKEY);
    scan2<<<1, 1024, 0, stream>>>(bsum, nbE, offsets, NKEY);
    scan3<<<nbE, 256, 0, stream>>>(offsets, bsum, cursor, NKEY);
    fill_kernel<<<(NE + 255) / 256, 256, 0, stream>>>(edge_src, edge_dst, edge_type, cursor, elist);

    int nbG = (NG + 255) / 256;
    ghist_kernel<<<(NN + 255) / 256, 256, 0, stream>>>(node2graph, gcounts);
    scan1<<<nbG, 256, 0, stream>>>(gcounts, goff, gbsum, NG);
    scan2<<<1, 1024, 0, stream>>>(gbsum, nbG, goff, NG);
    scan3<<<nbG, 256, 0, stream>>>(goff, gbsum, (int*)nullptr, NG);

    int rt = (NN + 63) / 64;  // 782
    for (int p = 0; p < NPASS; ++p) {
        agg4<<<(NKEY + 3) / 4, 256, 0, stream>>>(offsets, elist, Acat, X);
        msgs_gemm2<<<rt, 256, 0, stream>>>(X, WK, b_msg, offsets, Acat);
        gru_gemm<<<rt, 256, 0, stream>>>(Acat, WB, b512, hf);
    }

    attn_kernel<<<(NN + 3) / 4, 256, 0, stream>>>(hf, w_gate, b_gate, attn);
    segsum_kernel<<<NG, 128, 0, stream>>>(goff, attn, hf, sg, asumg);
    readout_kernel<<<NG, GHID, 0, stream>>>(sg, asumg, W_g, b_g, hgraph);
}